// Round 6
// baseline (229.527 us; speedup 1.0000x reference)
//
#include <hip/hip_runtime.h>

#define NUM_EMBED 1024
#define EMBED_DIM 256
#define SPATIAL 4096          // 64*64
#define NROWS 65536           // 16*4096
#define EMBED_ELEMS 16777216  // 16*256*4096
#define HMARGIN 0.05f         // margin on h = d2/2 scores (== 0.1 on d2)

typedef _Float16 half8 __attribute__((ext_vector_type(8)));
typedef float f32x4 __attribute__((ext_vector_type(4)));

__device__ __forceinline__ unsigned fkey(float f) {
  unsigned u = __float_as_uint(f);
  return (u & 0x80000000u) ? ~u : (u | 0x80000000u);
}

// ---------------- init: used, flagcount, cnorm, cb16 ----------------
__global__ __launch_bounds__(256) void k_init(const float* __restrict__ cb,
                                              int* __restrict__ used,
                                              int* __restrict__ flagcount,
                                              float* __restrict__ cnorm,
                                              _Float16* __restrict__ cb16) {
  int bid = blockIdx.x, tid = threadIdx.x;
  if (bid == 0) {
    used[tid] = 0; used[tid + 256] = 0; used[tid + 512] = 0; used[tid + 768] = 0;
    if (tid == 0) *flagcount = 0;
  } else if (bid <= 64) {
    int c = (bid - 1) * 16 + (tid >> 4);
    int l = tid & 15;
    const float4* p = (const float4*)(cb + c * EMBED_DIM + l * 16);
    float s = 0.f;
#pragma unroll
    for (int j = 0; j < 4; ++j) {
      float4 v = p[j];
      s += v.x * v.x + v.y * v.y + v.z * v.z + v.w * v.w;
    }
#pragma unroll
    for (int off = 1; off < 16; off <<= 1) s += __shfl_xor(s, off, 16);
    if (l == 0) cnorm[c] = s;
  } else {
    int gid = (bid - 65) * 256 + tid;  // 0..32767
    const float4* src = (const float4*)(cb + gid * 8);
    float4 a = src[0], b = src[1];
    half8 h;
    h[0] = (_Float16)a.x; h[1] = (_Float16)a.y; h[2] = (_Float16)a.z; h[3] = (_Float16)a.w;
    h[4] = (_Float16)b.x; h[5] = (_Float16)b.y; h[6] = (_Float16)b.z; h[7] = (_Float16)b.w;
    *(half8*)(cb16 + gid * 8) = h;
  }
}

// ---------------- fp16 MFMA screening, barrier-free main loop ----------------
// block: 128 rows = 4 waves x 32 rows. Each wave: X-fragments in registers
// (one-time wave-private LDS transpose), A-fragments loaded per chunk DIRECTLY
// from L2-resident cb16 into registers (compiler-counted vmcnt), 32 chunks of
// 32 codes x full K=256. No barriers, no LDS in the main loop.
__global__ __launch_bounds__(256, 2) void k_score(const float* __restrict__ in,
                                                  const _Float16* __restrict__ cb16,
                                                  const float* __restrict__ cnorm,
                                                  float* __restrict__ out_idx,
                                                  int* __restrict__ idxi,
                                                  int* __restrict__ flagged,
                                                  int* __restrict__ flagcount,
                                                  int* __restrict__ used) {
  __shared__ _Float16 Xs[4][8192];  // 64 KB: per-wave [kc 0..31][row 0..31] 16B
  __shared__ float cn_lds[1024];    // 4 KB, pre-scaled x0.5
  int tid = threadIdx.x;
  int lane = tid & 63;
  int wave = tid >> 6;
  int ln = lane & 15;
  int lg = lane >> 4;
  int r0 = blockIdx.x << 7;  // 128 rows/block
  const float* Ain = in + ((r0 >> 12) * (EMBED_DIM * SPATIAL)) + (r0 & 4095);

  // ---- one-time X transpose into this wave's private Xs quarter ----
  {
    int row = lane & 31;
    int khalf = lane >> 5;  // 0/1
    const float* p0 = Ain + wave * 32 + row;
    char* base = (char*)Xs[wave];
#pragma unroll
    for (int j = 0; j < 16; ++j) {
      int kc = khalf * 16 + j;  // 0..31
      half8 h;
#pragma unroll
      for (int q = 0; q < 8; ++q) h[q] = (_Float16)p0[(kc * 8 + q) * SPATIAL];
      *(half8*)(base + kc * 512 + row * 16) = h;
    }
  }
  // cnorm*0.5 -> LDS (cooperative; needs the one prologue barrier)
#pragma unroll
  for (int i = 0; i < 4; ++i) cn_lds[tid + 256 * i] = 0.5f * cnorm[tid + 256 * i];
  __syncthreads();  // only barrier in the kernel

  // ---- X fragments to registers: xf[ks][nf], k = ks*32 + lg*8, row = nf*16+ln ----
  half8 xf[8][2];
  {
    const char* xb = (const char*)Xs[wave];
#pragma unroll
    for (int ks = 0; ks < 8; ++ks)
#pragma unroll
      for (int nf = 0; nf < 2; ++nf)
        xf[ks][nf] = *(const half8*)(xb + (ks * 4 + lg) * 512 + (nf * 16 + ln) * 16);
  }

  // ---- A-fragment per-lane global base: code = c*32 + mf*16 + ln, k = ks*32 + lg*8
  const _Float16* pbase = cb16 + ln * 256 + lg * 8;

  float sv1[2] = {3e38f, 3e38f}, sv2[2] = {3e38f, 3e38f};
  int si1[2] = {0, 0};

  // prologue: chunk 0 A-fragments
  half8 pf[8][2];
#pragma unroll
  for (int ks = 0; ks < 8; ++ks)
#pragma unroll
    for (int mf = 0; mf < 2; ++mf)
      pf[ks][mf] = *(const half8*)(pbase + mf * 4096 + ks * 32);

#pragma unroll
  for (int c = 0; c < 32; ++c) {
    f32x4 acc[2][2] = {};
    __builtin_amdgcn_s_setprio(1);
#pragma unroll
    for (int ks = 0; ks < 8; ++ks) {
      acc[0][0] = __builtin_amdgcn_mfma_f32_16x16x32_f16(pf[ks][0], xf[ks][0], acc[0][0], 0, 0, 0);
      acc[0][1] = __builtin_amdgcn_mfma_f32_16x16x32_f16(pf[ks][0], xf[ks][1], acc[0][1], 0, 0, 0);
      acc[1][0] = __builtin_amdgcn_mfma_f32_16x16x32_f16(pf[ks][1], xf[ks][0], acc[1][0], 0, 0, 0);
      acc[1][1] = __builtin_amdgcn_mfma_f32_16x16x32_f16(pf[ks][1], xf[ks][1], acc[1][1], 0, 0, 0);
    }
    __builtin_amdgcn_s_setprio(0);
    // prefetch next chunk (register loads; compiler inserts counted vmcnt)
    if (c < 31) {
      const _Float16* pn = pbase + (c + 1) * 8192;
#pragma unroll
      for (int ks = 0; ks < 8; ++ks)
#pragma unroll
        for (int mf = 0; mf < 2; ++mf)
          pf[ks][mf] = *(const half8*)(pn + mf * 4096 + ks * 32);
    }
    // fold chunk: h = 0.5*|c|^2 - x.c  (argmin-equivalent to d2)
#pragma unroll
    for (int mf = 0; mf < 2; ++mf) {
      float cna[4];
      *(float4*)cna = *(const float4*)(cn_lds + c * 32 + mf * 16 + lg * 4);
#pragma unroll
      for (int nf = 0; nf < 2; ++nf) {
#pragma unroll
        for (int r = 0; r < 4; ++r) {
          float s = cna[r] - acc[mf][nf][r];
          int code = c * 32 + mf * 16 + lg * 4 + r;
          if (s < sv1[nf]) { sv2[nf] = sv1[nf]; sv1[nf] = s; si1[nf] = code; }
          else if (s < sv2[nf]) { sv2[nf] = s; }
        }
      }
    }
  }

  // ---- merge the 4 lane-groups (same rows, disjoint codes); no cross-wave ----
#pragma unroll
  for (int nf = 0; nf < 2; ++nf) {
#pragma unroll
    for (int off = 16; off < 64; off <<= 1) {
      float ov1 = __shfl_xor(sv1[nf], off);
      float ov2 = __shfl_xor(sv2[nf], off);
      int oi = __shfl_xor(si1[nf], off);
      if (ov1 < sv1[nf]) { sv2[nf] = fminf(sv1[nf], ov2); sv1[nf] = ov1; si1[nf] = oi; }
      else { sv2[nf] = fminf(sv2[nf], ov1); }
    }
  }
  if (lg == 0) {
#pragma unroll
    for (int nf = 0; nf < 2; ++nf) {
      int grow = r0 + wave * 32 + nf * 16 + ln;
      out_idx[grow] = (float)si1[nf];
      idxi[grow] = si1[nf];
      if (sv2[nf] - sv1[nf] < HMARGIN) {
        int p = atomicAdd(flagcount, 1);
        flagged[p] = grow;
      } else {
        used[si1[nf]] = 1;  // final winner for unflagged rows
      }
    }
  }
}

// ---------------- exact fp32 re-rank: 8 flagged rows per block ----------------
__global__ __launch_bounds__(256) void k_cleanup(const float* __restrict__ in,
                                                 const float* __restrict__ cb,
                                                 const float* __restrict__ cnorm,
                                                 const int* __restrict__ flagged,
                                                 const int* __restrict__ flagcount,
                                                 float* __restrict__ out_idx,
                                                 int* __restrict__ idxi,
                                                 int* __restrict__ used) {
  __shared__ float xs[8][256];
  __shared__ unsigned long long red[4][8];
  int tid = threadIdx.x;
  int lane = tid & 63;
  int wave = tid >> 6;
  int nf = *flagcount;
  const float4* cb4 = (const float4*)cb;
  for (int g = blockIdx.x; g * 8 < nf; g += 1024) {
    int base = g * 8;
    int cnt = nf - base; if (cnt > 8) cnt = 8;
    {
      int j = tid >> 5;
      int k0 = (tid & 31) * 8;
      int fi = base + j;
      int row = flagged[fi < nf ? fi : base];
      int b = row >> 12, s = row & 4095;
      const float* p = in + b * (EMBED_DIM * SPATIAL) + s;
#pragma unroll
      for (int q = 0; q < 8; ++q) xs[j][k0 + q] = p[(k0 + q) * SPATIAL];
    }
    __syncthreads();
    float acc[4][8] = {};
    for (int k4 = 0; k4 < 64; ++k4) {
      float4 cw[4];
#pragma unroll
      for (int i = 0; i < 4; ++i) cw[i] = cb4[(tid + 256 * i) * 64 + k4];
#pragma unroll
      for (int r = 0; r < 8; ++r) {
        float4 xv = *(const float4*)&xs[r][k4 * 4];
#pragma unroll
        for (int i = 0; i < 4; ++i)
          acc[i][r] += cw[i].x * xv.x + cw[i].y * xv.y + cw[i].z * xv.z + cw[i].w * xv.w;
      }
    }
    float cnl[4];
#pragma unroll
    for (int i = 0; i < 4; ++i) cnl[i] = cnorm[tid + 256 * i];
#pragma unroll
    for (int r = 0; r < 8; ++r) {
      unsigned long long b = ~0ull;
#pragma unroll
      for (int i = 0; i < 4; ++i) {
        float s = cnl[i] - 2.0f * acc[i][r];
        unsigned long long p =
            ((unsigned long long)fkey(s) << 32) | (unsigned)(tid + 256 * i);
        b = p < b ? p : b;
      }
#pragma unroll
      for (int off = 1; off < 64; off <<= 1) {
        unsigned long long o = __shfl_xor(b, off);
        b = o < b ? o : b;
      }
      if (lane == 0) red[wave][r] = b;
    }
    __syncthreads();
    if (tid < cnt) {
      unsigned long long b = red[0][tid];
#pragma unroll
      for (int w = 1; w < 4; ++w) { unsigned long long o = red[w][tid]; b = o < b ? o : b; }
      int row = flagged[base + tid];
      int idx = (int)(b & 0xffffffffull);
      out_idx[row] = (float)idx;
      idxi[row] = idx;
      used[idx] = 1;
    }
    __syncthreads();
  }
}

// ---------------- gather embed + MSE partial sums ----------------
__global__ __launch_bounds__(256) void k_gather(const float* __restrict__ in,
                                                const float* __restrict__ cb,
                                                const int* __restrict__ idxi,
                                                float* __restrict__ embed_out,
                                                double* __restrict__ partials) {
  int tid = threadIdx.x;
  float lsum = 0.f;
#pragma unroll
  for (int it = 0; it < 4; ++it) {
    int gid = (it * 4096 + blockIdx.x) * 256 + tid;
    int b = gid >> 18;
    int r = gid & 262143;
    int d = r >> 10;
    int s4 = r & 1023;
    int4 id4 = *(const int4*)(idxi + (b << 12) + (s4 << 2));
    int off = ((b * EMBED_DIM + d) << 12) + (s4 << 2);
    float4 x = *(const float4*)(in + off);
    float4 e;
    e.x = cb[id4.x * EMBED_DIM + d];
    e.y = cb[id4.y * EMBED_DIM + d];
    e.z = cb[id4.z * EMBED_DIM + d];
    e.w = cb[id4.w * EMBED_DIM + d];
    *(float4*)(embed_out + off) = e;
    float dx = e.x - x.x, dy = e.y - x.y, dz = e.z - x.z, dw = e.w - x.w;
    lsum += dx * dx + dy * dy + dz * dz + dw * dw;
  }
#pragma unroll
  for (int off = 1; off < 64; off <<= 1) lsum += __shfl_xor(lsum, off, 64);
  __shared__ float wsum[4];
  if ((tid & 63) == 0) wsum[tid >> 6] = lsum;
  __syncthreads();
  if (tid == 0)
    partials[blockIdx.x] = (double)(wsum[0] + wsum[1] + wsum[2] + wsum[3]);
}

// ---------------- tail: loss scalar + new_last_used ----------------
__global__ __launch_bounds__(256) void k_tail(const double* __restrict__ partials,
                                              const int* __restrict__ used,
                                              const int* __restrict__ last_used,
                                              float* __restrict__ out_loss,
                                              float* __restrict__ out_lu) {
  int tid = threadIdx.x;
  double s = 0.0;
  for (int i = tid; i < 4096; i += 256) s += partials[i];
#pragma unroll
  for (int off = 1; off < 64; off <<= 1) s += __shfl_xor(s, off, 64);
  __shared__ double sd[4];
  if ((tid & 63) == 0) sd[tid >> 6] = s;
  __syncthreads();
  if (tid == 0) {
    double total = sd[0] + sd[1] + sd[2] + sd[3];
    out_loss[0] = (float)(1.25 * total / (double)EMBED_ELEMS);
  }
  for (int i = tid; i < NUM_EMBED; i += 256)
    out_lu[i] = used[i] ? 0.0f : (float)(last_used[i] + 1);
}

extern "C" void kernel_launch(void* const* d_in, const int* in_sizes, int n_in,
                              void* d_out, int out_size, void* d_ws, size_t ws_size,
                              hipStream_t stream) {
  const float* in = (const float*)d_in[0];
  const float* cb = (const float*)d_in[1];
  const int* last_used = (const int*)d_in[2];

  float* out = (float*)d_out;
  float* out_idx = out;                       // 65536
  float* embed_out = out + NROWS;             // 16777216
  float* out_loss = embed_out + EMBED_ELEMS;  // 1
  float* out_lu = out_loss + 1;               // 1024

  _Float16* cb16 = (_Float16*)d_ws;                            // 512 KB
  double* partials = (double*)(cb16 + NUM_EMBED * EMBED_DIM);  // 4096 double
  int* flagged = (int*)(partials + 4096);                      // 65536 int
  int* flagcount = flagged + NROWS;                            // 16 int
  int* idxi = flagcount + 16;                                  // 65536 int
  int* used = idxi + NROWS;                                    // 1024 int
  float* cnorm = (float*)(used + NUM_EMBED);                   // 1024 float

  hipLaunchKernelGGL(k_init, dim3(193), dim3(256), 0, stream, cb, used, flagcount, cnorm, cb16);
  hipLaunchKernelGGL(k_score, dim3(512), dim3(256), 0, stream, in, cb16, cnorm, out_idx,
                     idxi, flagged, flagcount, used);
  hipLaunchKernelGGL(k_cleanup, dim3(1024), dim3(256), 0, stream, in, cb, cnorm, flagged,
                     flagcount, out_idx, idxi, used);
  hipLaunchKernelGGL(k_gather, dim3(4096), dim3(256), 0, stream, in, cb, idxi, embed_out,
                     partials);
  hipLaunchKernelGGL(k_tail, dim3(1), dim3(256), 0, stream, partials, used, last_used,
                     out_loss, out_lu);
}

// Round 8
// 196.536 us; speedup vs baseline: 1.1679x; 1.1679x over previous
//
#include <hip/hip_runtime.h>

#define NUM_EMBED 1024
#define EMBED_DIM 256
#define SPATIAL 4096          // 64*64
#define NROWS 65536           // 16*4096
#define EMBED_ELEMS 16777216  // 16*256*4096
#define HMARGIN 0.05f         // margin on h = d2/2 scores (== 0.1 on d2)

typedef _Float16 half8 __attribute__((ext_vector_type(8)));
typedef float f32x4 __attribute__((ext_vector_type(4)));

__device__ __forceinline__ unsigned fkey(float f) {
  unsigned u = __float_as_uint(f);
  return (u & 0x80000000u) ? ~u : (u | 0x80000000u);
}

__device__ __forceinline__ void gll16(const _Float16* g, void* l) {
  __builtin_amdgcn_global_load_lds((const __attribute__((address_space(1))) void*)g,
                                   (__attribute__((address_space(3))) void*)l, 16, 0, 0);
}

// min1/min2/idx update with a new (s, i)
#define UPD(V1, V2, I1, S, I)                            \
  { if ((S) < (V1)) { (V2) = (V1); (V1) = (S); (I1) = (I); } \
    else if ((S) < (V2)) { (V2) = (S); } }

// merge (v1b,v2b,i1b) into (v1a,v2a,i1a); ties keep A (lower code ids live in A)
#define MERGE(V1A, V2A, I1A, V1B, V2B, I1B)                       \
  { if ((V1B) < (V1A)) { (V2A) = fminf((V1A), (V2B)); (V1A) = (V1B); (I1A) = (I1B); } \
    else { (V2A) = fminf((V2A), (V1B)); } }

// ---------------- init: used, flagcount, cnorm, cb16 ----------------
__global__ __launch_bounds__(256) void k_init(const float* __restrict__ cb,
                                              int* __restrict__ used,
                                              int* __restrict__ flagcount,
                                              float* __restrict__ cnorm,
                                              _Float16* __restrict__ cb16) {
  int bid = blockIdx.x, tid = threadIdx.x;
  if (bid == 0) {
    used[tid] = 0; used[tid + 256] = 0; used[tid + 512] = 0; used[tid + 768] = 0;
    if (tid == 0) *flagcount = 0;
  } else if (bid <= 64) {
    int c = (bid - 1) * 16 + (tid >> 4);
    int l = tid & 15;
    const float4* p = (const float4*)(cb + c * EMBED_DIM + l * 16);
    float s = 0.f;
#pragma unroll
    for (int j = 0; j < 4; ++j) {
      float4 v = p[j];
      s += v.x * v.x + v.y * v.y + v.z * v.z + v.w * v.w;
    }
#pragma unroll
    for (int off = 1; off < 16; off <<= 1) s += __shfl_xor(s, off, 16);
    if (l == 0) cnorm[c] = s;
  } else {
    int gid = (bid - 65) * 256 + tid;  // 0..32767
    const float4* src = (const float4*)(cb + gid * 8);
    float4 a = src[0], b = src[1];
    half8 h;
    h[0] = (_Float16)a.x; h[1] = (_Float16)a.y; h[2] = (_Float16)a.z; h[3] = (_Float16)a.w;
    h[4] = (_Float16)b.x; h[5] = (_Float16)b.y; h[6] = (_Float16)b.z; h[7] = (_Float16)b.w;
    *(half8*)(cb16 + gid * 8) = h;
  }
}

// ---------------- fp16 MFMA screening (R5 data path, ROLLED main loop) ----------------
// block: 128 rows = 4 waves x 32 rows. X-fragments in registers (one-time LDS
// transpose), codebook chunks (32 codes x K=256, 16 KB each) staged by
// global_load_lds into a 3-deep LDS ring (byte offsets 0/16384/32768), counted
// vmcnt(4), one raw s_barrier per chunk. Main loop ROLLED for I$ residency.
__global__ __launch_bounds__(256, 2) void k_score(const float* __restrict__ in,
                                                  const _Float16* __restrict__ cb16,
                                                  const float* __restrict__ cnorm,
                                                  float* __restrict__ out_idx,
                                                  int* __restrict__ idxi,
                                                  int* __restrict__ flagged,
                                                  int* __restrict__ flagcount,
                                                  int* __restrict__ used) {
  __shared__ _Float16 As[3][8192];  // 48 KB ring (also transpose scratch)
  __shared__ float cn_lds[1024];    // 4 KB, pre-scaled x0.5
  int tid = threadIdx.x;
  int lane = tid & 63;
  int wave = tid >> 6;
  int ln = lane & 15;
  int lg = lane >> 4;
  int r0 = blockIdx.x << 7;  // 128 rows/block
  const float* Ain = in + ((r0 >> 12) * (EMBED_DIM * SPATIAL)) + (r0 & 4095);

  // ---- one-time X transpose: wave w stages its 32 rows, reads back fragments ----
  half8 xf[8][2];
  {
    int row = lane & 31;
    int khalf = lane >> 5;  // 0/1
    const float* p0 = Ain + wave * 32 + row;
    if (wave < 3) {
      char* base = (char*)As[wave];
#pragma unroll
      for (int j = 0; j < 16; ++j) {
        int kc = khalf * 16 + j;
        half8 h;
#pragma unroll
        for (int q = 0; q < 8; ++q) h[q] = (_Float16)p0[(kc * 8 + q) * SPATIAL];
        *(half8*)(base + kc * 512 + row * 16) = h;
      }
    }
    // cnorm*0.5 -> LDS (cooperative)
#pragma unroll
    for (int i = 0; i < 4; ++i) cn_lds[tid + 256 * i] = 0.5f * cnorm[tid + 256 * i];
    __syncthreads();
    if (wave < 3) {
      const char* base = (const char*)As[wave];
#pragma unroll
      for (int ks = 0; ks < 8; ++ks)
#pragma unroll
        for (int nf = 0; nf < 2; ++nf)
          xf[ks][nf] = *(const half8*)(base + (ks * 4 + lg) * 512 + (nf * 16 + ln) * 16);
    }
    __syncthreads();  // waves 0..2 done reading before wave 3 reuses As[0]
    if (wave == 3) {
      char* base = (char*)As[0];
#pragma unroll
      for (int j = 0; j < 16; ++j) {
        int kc = khalf * 16 + j;
        half8 h;
#pragma unroll
        for (int q = 0; q < 8; ++q) h[q] = (_Float16)p0[(kc * 8 + q) * SPATIAL];
        *(half8*)(base + kc * 512 + row * 16) = h;
      }
      const char* cbase2 = (const char*)As[0];
#pragma unroll
      for (int ks = 0; ks < 8; ++ks)
#pragma unroll
        for (int nf = 0; nf < 2; ++nf)
          xf[ks][nf] = *(const half8*)(cbase2 + (ks * 4 + lg) * 512 + (nf * 16 + ln) * 16);
    }
    __syncthreads();  // As free for codebook ring
  }

  // per-thread gll16 source base: code (t&31), k-slot (t>>5); chunk stride 8192 halves
  const _Float16* pc = cb16 + (tid & 31) * 256 + (tid >> 5) * 8;
  char* AsB = (char*)As[0];
  int dsto = tid * 16;

  // prologue: chunks 0,1 -> ring buffers 0,1 (buffers are 16384 BYTES apart)
#pragma unroll
  for (int i = 0; i < 4; ++i) gll16(pc + i * 64, AsB + i * 4096 + dsto);
#pragma unroll
  for (int i = 0; i < 4; ++i) gll16(pc + 8192 + i * 64, AsB + 16384 + i * 4096 + dsto);

  float sv1[2] = {3e38f, 3e38f}, sv2[2] = {3e38f, 3e38f};
  int si1[2] = {0, 0};

  const _Float16* pnext = pc + 2 * 8192;  // gll source for chunk c+2 (halves)
  int cur = 0;                            // ring BYTE offset of chunk c: {0,16384,32768}
  int nxt2 = 32768;                       // ring BYTE offset of chunk c+2
  int cbase = 0;                          // first code id of chunk c
  int afo0 = lg * 512 + ln * 16;          // A-frag offset within buffer (+ks*2048, +mf*256)

#pragma unroll 1
  for (int c = 0; c < 32; ++c) {
    if (c < 31) { asm volatile("s_waitcnt vmcnt(4)" ::: "memory"); }
    else        { asm volatile("s_waitcnt vmcnt(0)" ::: "memory"); }
    __builtin_amdgcn_s_barrier();
    asm volatile("" ::: "memory");
    if (c < 30) {
      char* dst = AsB + nxt2;
#pragma unroll
      for (int i = 0; i < 4; ++i) gll16(pnext + i * 64, dst + i * 4096 + dsto);
      pnext += 8192;
    }
    const char* Ac = AsB + cur;
    f32x4 acc[2][2] = {};
    __builtin_amdgcn_s_setprio(1);
#pragma unroll
    for (int ks = 0; ks < 8; ++ks) {
      half8 af0 = *(const half8*)(Ac + ks * 2048 + afo0);
      half8 af1 = *(const half8*)(Ac + ks * 2048 + afo0 + 256);
      acc[0][0] = __builtin_amdgcn_mfma_f32_16x16x32_f16(af0, xf[ks][0], acc[0][0], 0, 0, 0);
      acc[0][1] = __builtin_amdgcn_mfma_f32_16x16x32_f16(af0, xf[ks][1], acc[0][1], 0, 0, 0);
      acc[1][0] = __builtin_amdgcn_mfma_f32_16x16x32_f16(af1, xf[ks][0], acc[1][0], 0, 0, 0);
      acc[1][1] = __builtin_amdgcn_mfma_f32_16x16x32_f16(af1, xf[ks][1], acc[1][1], 0, 0, 0);
    }
    __builtin_amdgcn_s_setprio(0);
    // fold chunk: h = 0.5*|c|^2 - x.c ; two 4-deep chains per nf, then merges
    float cna[4], cnb[4];
    *(float4*)cna = *(const float4*)(cn_lds + cbase + lg * 4);
    *(float4*)cnb = *(const float4*)(cn_lds + cbase + 16 + lg * 4);
    int ib0 = cbase + lg * 4;
#pragma unroll
    for (int nf = 0; nf < 2; ++nf) {
      float v1a = cna[0] - acc[0][nf][0], v2a = 3e38f;
      int i1a = ib0;
      float v1b = cnb[0] - acc[1][nf][0], v2b = 3e38f;
      int i1b = ib0 + 16;
#pragma unroll
      for (int r = 1; r < 4; ++r) {
        float sa = cna[r] - acc[0][nf][r];
        UPD(v1a, v2a, i1a, sa, ib0 + r);
        float sb = cnb[r] - acc[1][nf][r];
        UPD(v1b, v2b, i1b, sb, ib0 + 16 + r);
      }
      MERGE(v1a, v2a, i1a, v1b, v2b, i1b);
      MERGE(sv1[nf], sv2[nf], si1[nf], v1a, v2a, i1a);
    }
    cbase += 32;
    cur += 16384; if (cur == 49152) cur = 0;
    nxt2 += 16384; if (nxt2 == 49152) nxt2 = 0;
  }

  // ---- merge the 4 lane-groups (same rows, disjoint codes); no cross-wave ----
#pragma unroll
  for (int nf = 0; nf < 2; ++nf) {
#pragma unroll
    for (int off = 16; off < 64; off <<= 1) {
      float ov1 = __shfl_xor(sv1[nf], off);
      float ov2 = __shfl_xor(sv2[nf], off);
      int oi = __shfl_xor(si1[nf], off);
      if (ov1 < sv1[nf]) { sv2[nf] = fminf(sv1[nf], ov2); sv1[nf] = ov1; si1[nf] = oi; }
      else { sv2[nf] = fminf(sv2[nf], ov1); }
    }
  }
  if (lg == 0) {
#pragma unroll
    for (int nf = 0; nf < 2; ++nf) {
      int grow = r0 + wave * 32 + nf * 16 + ln;
      out_idx[grow] = (float)si1[nf];
      idxi[grow] = si1[nf];
      if (sv2[nf] - sv1[nf] < HMARGIN) {
        int p = atomicAdd(flagcount, 1);
        flagged[p] = grow;
      } else {
        used[si1[nf]] = 1;  // final winner for unflagged rows
      }
    }
  }
}

// ---------------- exact fp32 re-rank: 1 flagged row per block, wave-per-code-slice ----------------
__global__ __launch_bounds__(256) void k_cleanup(const float* __restrict__ in,
                                                 const float* __restrict__ cb,
                                                 const float* __restrict__ cnorm,
                                                 const int* __restrict__ flagged,
                                                 const int* __restrict__ flagcount,
                                                 float* __restrict__ out_idx,
                                                 int* __restrict__ idxi,
                                                 int* __restrict__ used) {
  __shared__ unsigned long long red[4];
  int tid = threadIdx.x;
  int lane = tid & 63;
  int wave = tid >> 6;
  int nf = *flagcount;
  const float4* cb4 = (const float4*)cb;  // cb4[code*64 + lane] = 16B of code row
  for (int fi = blockIdx.x; fi < nf; fi += 2048) {
    int row = flagged[fi];
    int b = row >> 12, s = row & 4095;
    const float* xp = in + b * (EMBED_DIM * SPATIAL) + s;
    float xk[4];
#pragma unroll
    for (int j = 0; j < 4; ++j) xk[j] = xp[(lane * 4 + j) * SPATIAL];
    unsigned long long best = ~0ull;
    int c0 = wave * 256;
#pragma unroll 4
    for (int cc = 0; cc < 256; ++cc) {
      int code = c0 + cc;
      float4 cv = cb4[code * 64 + lane];  // coalesced: 64 lanes x 16B
      float p = cv.x * xk[0] + cv.y * xk[1] + cv.z * xk[2] + cv.w * xk[3];
#pragma unroll
      for (int off = 1; off < 64; off <<= 1) p += __shfl_xor(p, off);
      float sc = cnorm[code] - 2.0f * p;
      unsigned long long k = ((unsigned long long)fkey(sc) << 32) | (unsigned)code;
      best = k < best ? k : best;
    }
    if (lane == 0) red[wave] = best;
    __syncthreads();
    if (tid == 0) {
      unsigned long long bb = red[0];
#pragma unroll
      for (int w = 1; w < 4; ++w) { unsigned long long o = red[w]; bb = o < bb ? o : bb; }
      int idx = (int)(bb & 0xffffffffull);
      out_idx[row] = (float)idx;
      idxi[row] = idx;
      used[idx] = 1;
    }
    __syncthreads();
  }
}

// ---------------- gather embed + MSE partial sums ----------------
__global__ __launch_bounds__(256) void k_gather(const float* __restrict__ in,
                                                const float* __restrict__ cb,
                                                const int* __restrict__ idxi,
                                                float* __restrict__ embed_out,
                                                double* __restrict__ partials) {
  int tid = threadIdx.x;
  float lsum = 0.f;
#pragma unroll
  for (int it = 0; it < 4; ++it) {
    int gid = (it * 4096 + blockIdx.x) * 256 + tid;
    int b = gid >> 18;
    int r = gid & 262143;
    int d = r >> 10;
    int s4 = r & 1023;
    int4 id4 = *(const int4*)(idxi + (b << 12) + (s4 << 2));
    int off = ((b * EMBED_DIM + d) << 12) + (s4 << 2);
    float4 x = *(const float4*)(in + off);
    float4 e;
    e.x = cb[id4.x * EMBED_DIM + d];
    e.y = cb[id4.y * EMBED_DIM + d];
    e.z = cb[id4.z * EMBED_DIM + d];
    e.w = cb[id4.w * EMBED_DIM + d];
    *(float4*)(embed_out + off) = e;
    float dx = e.x - x.x, dy = e.y - x.y, dz = e.z - x.z, dw = e.w - x.w;
    lsum += dx * dx + dy * dy + dz * dz + dw * dw;
  }
#pragma unroll
  for (int off = 1; off < 64; off <<= 1) lsum += __shfl_xor(lsum, off, 64);
  __shared__ float wsum[4];
  if ((tid & 63) == 0) wsum[tid >> 6] = lsum;
  __syncthreads();
  if (tid == 0)
    partials[blockIdx.x] = (double)(wsum[0] + wsum[1] + wsum[2] + wsum[3]);
}

// ---------------- tail: loss scalar + new_last_used ----------------
__global__ __launch_bounds__(256) void k_tail(const double* __restrict__ partials,
                                              const int* __restrict__ used,
                                              const int* __restrict__ last_used,
                                              float* __restrict__ out_loss,
                                              float* __restrict__ out_lu) {
  int tid = threadIdx.x;
  double s = 0.0;
  for (int i = tid; i < 4096; i += 256) s += partials[i];
#pragma unroll
  for (int off = 1; off < 64; off <<= 1) s += __shfl_xor(s, off, 64);
  __shared__ double sd[4];
  if ((tid & 63) == 0) sd[tid >> 6] = s;
  __syncthreads();
  if (tid == 0) {
    double total = sd[0] + sd[1] + sd[2] + sd[3];
    out_loss[0] = (float)(1.25 * total / (double)EMBED_ELEMS);
  }
  for (int i = tid; i < NUM_EMBED; i += 256)
    out_lu[i] = used[i] ? 0.0f : (float)(last_used[i] + 1);
}

extern "C" void kernel_launch(void* const* d_in, const int* in_sizes, int n_in,
                              void* d_out, int out_size, void* d_ws, size_t ws_size,
                              hipStream_t stream) {
  const float* in = (const float*)d_in[0];
  const float* cb = (const float*)d_in[1];
  const int* last_used = (const int*)d_in[2];

  float* out = (float*)d_out;
  float* out_idx = out;                       // 65536
  float* embed_out = out + NROWS;             // 16777216
  float* out_loss = embed_out + EMBED_ELEMS;  // 1
  float* out_lu = out_loss + 1;               // 1024

  _Float16* cb16 = (_Float16*)d_ws;                            // 512 KB
  double* partials = (double*)(cb16 + NUM_EMBED * EMBED_DIM);  // 4096 double
  int* flagged = (int*)(partials + 4096);                      // 65536 int
  int* flagcount = flagged + NROWS;                            // 16 int
  int* idxi = flagcount + 16;                                  // 65536 int
  int* used = idxi + NROWS;                                    // 1024 int
  float* cnorm = (float*)(used + NUM_EMBED);                   // 1024 float

  hipLaunchKernelGGL(k_init, dim3(193), dim3(256), 0, stream, cb, used, flagcount, cnorm, cb16);
  hipLaunchKernelGGL(k_score, dim3(512), dim3(256), 0, stream, in, cb16, cnorm, out_idx,
                     idxi, flagged, flagcount, used);
  hipLaunchKernelGGL(k_cleanup, dim3(2048), dim3(256), 0, stream, in, cb, cnorm, flagged,
                     flagcount, out_idx, idxi, used);
  hipLaunchKernelGGL(k_gather, dim3(4096), dim3(256), 0, stream, in, cb, idxi, embed_out,
                     partials);
  hipLaunchKernelGGL(k_tail, dim3(1), dim3(256), 0, stream, partials, used, last_used,
                     out_loss, out_lu);
}